// Round 18
// baseline (315.890 us; speedup 1.0000x reference)
//
#include <hip/hip_runtime.h>
#include <cstdint>
#include <cstddef>

// Problem constants
#define BATCH 4
#define SEQ   2048
#define CMOD  1024
#define NH    16
#define DH    64
#define LOG100 4.6051701859880914f
#define LOG2E  1.4426950408889634f

typedef __attribute__((ext_vector_type(8))) short bf16x8;
typedef __attribute__((ext_vector_type(4))) float f32x4;
typedef __attribute__((ext_vector_type(16))) float f32x16;

__device__ __forceinline__ float u32lo_f(uint32_t u) {
    union { uint32_t i; float f; } x; x.i = u << 16; return x.f;
}
__device__ __forceinline__ float u32hi_f(uint32_t u) {
    union { uint32_t i; float f; } x; x.i = u & 0xFFFF0000u; return x.f;
}
__device__ __forceinline__ uint16_t f2bf(float f) {
    union { float f; uint32_t i; } x; x.f = f;
    uint32_t u = x.i;
    return (uint16_t)((u + 0x7FFFu + ((u >> 16) & 1u)) >> 16);  // RNE
}
__device__ __forceinline__ float exp2_fast(float x) {
    float r; asm("v_exp_f32 %0, %1" : "=v"(r) : "v"(x)); return r;
}
__device__ __forceinline__ uint32_t cvt_pk_bf16(float lo, float hi) {
    uint32_t r;
    asm("v_cvt_pk_bf16_f32 %0, %1, %2" : "=v"(r) : "v"(lo), "v"(hi));
    return r;
}
__device__ __forceinline__ void p32swap(uint32_t& x, uint32_t& y) {
#if __has_builtin(__builtin_amdgcn_permlane32_swap)
    auto r = __builtin_amdgcn_permlane32_swap(x, y, false, false);
    x = r[0]; y = r[1];
#else
    asm volatile("v_permlane32_swap_b32 %0, %1\n\ts_nop 1" : "+v"(x), "+v"(y));
#endif
}

__device__ __forceinline__ void gload_lds16(const void* g, void* l) {
    __builtin_amdgcn_global_load_lds(
        (const __attribute__((address_space(1))) uint32_t*)g,
        (__attribute__((address_space(3))) uint32_t*)l,
        16, 0, 0);
}

// ---------------- fp32 -> bf16 convert ----------------
__global__ __launch_bounds__(256) void cvt_kernel(const float* __restrict__ in,
                                                  uint16_t* __restrict__ out, int n) {
    int i = (blockIdx.x * 256 + threadIdx.x) * 4;
    if (i >= n) return;
    float4 f = *(const float4*)(in + i);
    ushort4 o;
    o.x = f2bf(f.x); o.y = f2bf(f.y); o.z = f2bf(f.z); o.w = f2bf(f.w);
    *(ushort4*)(out + i) = o;
}

// ---------------- bf16 GEMM, B-transposed input (m97 structure) ----------------
// mode 0: QKV epilogue. q/k normalized (q also * scale_h*log2e), then written in
// MFMA-FRAGMENT ORDER so attention can stage/load with lane-linear coalesced access:
//   q/k: addr = ((bh*64 + (l>>5))*4 + (d>>4))*512 + ((d>>3)&1)*256 + (l&31)*8 + (d&7)
//   v  : addr = ((bh*64 + (l>>5))*4 + (d>>5)*2 + ((l>>4)&1))*512
//               + (((l>>3)&1)*32 + (d&31))*8 + (l&7)
// mode 1: proj epilogue -> fp32 out + b_proj (unchanged).
__global__ __launch_bounds__(256) void gemm_bt_kernel(
    const uint16_t* __restrict__ A, const uint16_t* __restrict__ B,
    int M, int N, int K, int mode,
    uint16_t* __restrict__ qb, uint16_t* __restrict__ kb, uint16_t* __restrict__ vtb,
    const float* __restrict__ q_bias, const float* __restrict__ v_bias,
    const float* __restrict__ scale_mul_log,
    float* __restrict__ outp, const float* __restrict__ b_proj)
{
    __shared__ __align__(16) uint16_t As[128 * 32];
    __shared__ __align__(16) uint16_t Bs[128 * 32];
    const int t = threadIdx.x;
    const int wave = t >> 6, lane = t & 63;
    const int g = lane >> 4, c16 = lane & 15;
    const int m0 = blockIdx.x * 128, n0 = blockIdx.y * 128;
    const int wm = (wave >> 1) * 64, wn = (wave & 1) * 64;

    f32x4 acc[4][4];
#pragma unroll
    for (int mt = 0; mt < 4; mt++)
#pragma unroll
        for (int nt = 0; nt < 4; nt++) acc[mt][nt] = (f32x4){0.f, 0.f, 0.f, 0.f};

    for (int k0 = 0; k0 < K; k0 += 32) {
        __syncthreads();
#pragma unroll
        for (int i = 0; i < 2; i++) {
            int cc = i * 256 + t;           // 512 chunks of 8 elems
            int row = cc >> 2, col = (cc & 3) * 8;
            gload_lds16(A + (size_t)(m0 + row) * K + k0 + col, &As[cc * 8]);
            gload_lds16(B + (size_t)(n0 + row) * K + k0 + col, &Bs[cc * 8]);
        }
        __syncthreads();
        bf16x8 af[4], bfv[4];
#pragma unroll
        for (int mt = 0; mt < 4; mt++)
            af[mt] = *(const bf16x8*)&As[(wm + mt * 16 + c16) * 32 + g * 8];
#pragma unroll
        for (int nt = 0; nt < 4; nt++)
            bfv[nt] = *(const bf16x8*)&Bs[(wn + nt * 16 + c16) * 32 + g * 8];
#pragma unroll
        for (int mt = 0; mt < 4; mt++)
#pragma unroll
            for (int nt = 0; nt < 4; nt++)
                acc[mt][nt] = __builtin_amdgcn_mfma_f32_16x16x32_bf16(af[mt], bfv[nt], acc[mt][nt], 0, 0, 0);
    }

    if (mode == 0) {
        const int colbase = n0 + wn;          // multiple of 64 -> single (tt, head) per wave
        const int tt = colbase >> 10;
        const int cc0 = colbase & 1023;
        const int hh = cc0 >> 6;
        float qmul = 1.0f;
        if (tt == 0) qmul = __expf(fminf(scale_mul_log[hh], LOG100)) * LOG2E;
#pragma unroll
        for (int mt = 0; mt < 4; mt++) {
            float vals[4][4];
            float n2[4] = {0.f, 0.f, 0.f, 0.f};
#pragma unroll
            for (int nt = 0; nt < 4; nt++) {
                const int ci = cc0 + nt * 16 + c16;   // 0..1023 within qkv third
                float badd = 0.f;
                if (tt == 0) badd = q_bias[ci];
                else if (tt == 2) badd = v_bias[ci];
#pragma unroll
                for (int r = 0; r < 4; r++) {
                    float v = acc[mt][nt][r] + badd;
                    vals[nt][r] = v;
                    n2[r] += v * v;
                }
            }
            float rs[4];
            if (tt < 2) {   // L2-normalize q (with scale*log2e) and k over the 64-wide head dim
#pragma unroll
                for (int r = 0; r < 4; r++) {
                    float s = n2[r];
                    s += __shfl_xor(s, 1, 64);
                    s += __shfl_xor(s, 2, 64);
                    s += __shfl_xor(s, 4, 64);
                    s += __shfl_xor(s, 8, 64);
                    rs[r] = qmul / fmaxf(sqrtf(s), 1e-12f);
                }
            } else {
#pragma unroll
                for (int r = 0; r < 4; r++) rs[r] = 1.0f;
            }
#pragma unroll
            for (int nt = 0; nt < 4; nt++) {
                const int dd = (cc0 + nt * 16 + c16) & 63;
#pragma unroll
                for (int r = 0; r < 4; r++) {
                    const int row = m0 + wm + mt * 16 + g * 4 + r;   // b*2048 + l
                    const int bb = row >> 11, ll = row & 2047;
                    const size_t bhx = (size_t)bb * NH + hh;
                    const uint16_t val = f2bf(vals[nt][r] * rs[r]);
                    if (tt < 2) {
                        size_t addr = ((bhx * 64 + (ll >> 5)) * 4 + (dd >> 4)) * 512
                                      + ((dd >> 3) & 1) * 256 + (ll & 31) * 8 + (dd & 7);
                        if (tt == 0) qb[addr] = val; else kb[addr] = val;
                    } else {
                        size_t addr = ((bhx * 64 + (ll >> 5)) * 4 + (dd >> 5) * 2 + ((ll >> 4) & 1)) * 512
                                      + (((ll >> 3) & 1) * 32 + (dd & 31)) * 8 + (ll & 7);
                        vtb[addr] = val;
                    }
                }
            }
        }
    } else {
#pragma unroll
        for (int mt = 0; mt < 4; mt++)
#pragma unroll
            for (int nt = 0; nt < 4; nt++)
#pragma unroll
                for (int r = 0; r < 4; r++) {
                    int row = m0 + wm + mt * 16 + g * 4 + r;
                    int col = n0 + wn + nt * 16 + c16;
                    outp[(size_t)row * N + col] = acc[mt][nt][r] + b_proj[col];
                }
    }
}

// ---------------- fused cosine-sim flash attention (KVBLK=64, 32 iters) ----------------
// grid: 512 blocks, XCD-pinned heads (R16, proven). block: 8 waves (512 thr):
// wave w8 -> batch b=w8&3, qhalf=w8>>2 (32 q-rows each).
// CHANGE vs R16: KVBLK=64 -> 32 iterations (was 64). Across R11-R17 the per-iter cost
// was a constant ~5500-5900 cyc regardless of content (structural: 8-wave barrier
// convergence + drain + serial chain) vs ~900 cyc of pipe work -> halving iteration
// count amortizes the overhead over 2x work.
// Per iter: K dbuf LDS (2x32KB, 4 gloads/wave across all 8 waves, frag-linear,
// conflict-free); V register-direct per 32-k sub-tile (vf0 at iter top, vf1 after
// kb2=0's S-MFMA -> counted vmcnt leaves younger ops flying); bias [64q][64k] via
// 2 float4/thread -> dbuf Bsh[2][2][512] (same unit scheme per sub-tile).
// Core per kb2: swapped mfma(K,Q) 32x32x16, static-max softmax, cvt_pk+permlane32
// repack (m214-v22), PV. setprio around MFMA clusters. Numerics identical (passed).
__global__ __launch_bounds__(512, 4) void attn_kernel(
    const uint16_t* __restrict__ qfrag, const uint16_t* __restrict__ kfrag,
    const uint16_t* __restrict__ vfrag, const float* __restrict__ bias,
    uint16_t* __restrict__ ob)
{
    __shared__ __align__(16) uint16_t KsL[2 * 4 * 8 * 512];  // [buf][batch][slot8][lane*8] 64 KB
    __shared__ __align__(16) uint2    Bsh[2 * 2 * 512];      // [buf][kb2][unit] bf16x4, 16 KB

    const int t = threadIdx.x;
    const int w8 = t >> 6, lane = t & 63;
    const int b = w8 & 3, qhalf = w8 >> 2;     // batch, q-half of the 64-row tile
    const int c32 = lane & 31, hi = lane >> 5;

    // XCD-pinned (h, qt) decode
    const int bid = blockIdx.x;
    const int xcd = bid & 7;
    const int inner = bid >> 3;                // 0..63
    const int h = xcd * 2 + (inner & 1);       // 0..15
    const int qt = inner >> 1;                 // 0..31
    const int q0w = qt * 64 + qhalf * 32;      // this wave's 32 q-rows
    const size_t bh = (size_t)b * NH + h;

    // Q fragments: 4 d-slots for this wave's 32 rows (frag-ordered workspace)
    bf16x8 qf[4];
#pragma unroll
    for (int s = 0; s < 4; s++)
        qf[s] = *(const bf16x8*)(qfrag +
            ((bh * 64 + (size_t)(qt * 2 + qhalf)) * 4 + s) * 512 + hi * 256 + c32 * 8);

    // K staging: 32 units (batch x 8 slots) split 4 per wave; slot sl = (tl_off<<2)|s
    auto stage = [&](int it2, int buf) {
#pragma unroll
        for (int j = 0; j < 4; j++) {
            int u = w8 * 4 + j;                // 0..31
            int bb = u >> 3, sl = u & 7;
            int tl = 2 * it2 + (sl >> 2), s = sl & 3;
            gload_lds16(kfrag + (((size_t)bb * NH + h) * 64 + tl) * 4 * 512 + s * 512 + lane * 8,
                        &KsL[((buf * 4 + bb) * 8 + sl) * 512 + lane * 8]);
        }
    };

    // V register-direct per 32-k sub-tile (frag-ordered; 64 lanes x 16B contiguous)
    const uint16_t* vbase = vfrag + ((bh * 64) * 4) * 512 + lane * 8;

    // bias: [64 rows][64 k] tile; thread t -> brow = t>>3, kch = t&7; 2 float4 at k=kch*8
    const int brow = t >> 3, kch = t & 7;
    const float* bgl = bias + ((size_t)h * SEQ + qt * 64 + brow) * SEQ + kch * 8;

    auto writeBsh = [&](int buf, float4 a, float4 b4) {
#pragma unroll
        for (int e = 0; e < 2; e++) {
            int g = kch * 2 + e;               // granule 0..15 (k = g*4..+4)
            int kb2 = g >> 3, gg = g & 7;
            int unit = (gg >> 1) * 128 + (brow >> 5) * 64 + (gg & 1) * 32 + (brow & 31);
            float4 v = e ? b4 : a;
            Bsh[(buf * 2 + kb2) * 512 + unit] =
                make_uint2(cvt_pk_bf16(v.x * LOG2E, v.y * LOG2E),
                           cvt_pk_bf16(v.z * LOG2E, v.w * LOG2E));
        }
    };

    f32x16 accO[2];
#pragma unroll
    for (int db = 0; db < 2; db++)
#pragma unroll
        for (int i = 0; i < 16; i++) accO[db][i] = 0.f;
    float lrun = 0.f;

    // prologue
    float4 a0 = *(const float4*)(bgl);
    float4 a1 = *(const float4*)(bgl + 4);
    float4 br0 = *(const float4*)(bgl + 64);
    float4 br1 = *(const float4*)(bgl + 68);
    stage(0, 0);
    writeBsh(0, a0, a1);
    __syncthreads();

    for (int it = 0; it < 32; ++it) {
        const int cur = it & 1;

        // V(kb2=0) direct loads at iter top: fly across stage-issue + S0-MFMA
        bf16x8 vf0[4];
        {
            const uint16_t* vp = vbase + ((size_t)(2 * it) * 4) * 512;
#pragma unroll
            for (int j = 0; j < 4; j++) vf0[j] = *(const bf16x8*)(vp + j * 512);
        }

        if (it < 31) {
            const int nb = cur ^ 1;
            writeBsh(nb, br0, br1);                       // bias(it+1) -> Bsh[nb]
            int n2 = it + 2; if (n2 > 31) n2 = 31;
            br0 = *(const float4*)(bgl + (size_t)n2 * 64);
            br1 = *(const float4*)(bgl + (size_t)n2 * 64 + 4);
            stage(it + 1, nb);                            // K DMA flies through compute
        }

        bf16x8 vf1[4];
        bf16x8 pa[2];

#pragma unroll
        for (int kb2 = 0; kb2 < 2; kb2++) {
            // K frags for this 32-k sub-tile (conflict-free lane-linear reads)
            bf16x8 kf[4];
#pragma unroll
            for (int s = 0; s < 4; s++)
                kf[s] = *(const bf16x8*)&KsL[((cur * 4 + b) * 8 + kb2 * 4 + s) * 512 + lane * 8];

            // S^T = K Q^T : reg r -> k_local = (r&3)+8*(r>>2)+4*hi ; q-row = c32
            f32x16 S;
#pragma unroll
            for (int i = 0; i < 16; i++) S[i] = 0.f;
            __builtin_amdgcn_s_setprio(1);
#pragma unroll
            for (int s = 0; s < 4; s++)
                S = __builtin_amdgcn_mfma_f32_32x32x16_bf16(kf[s], qf[s], S, 0, 0, 0);
            __builtin_amdgcn_s_setprio(0);

            if (kb2 == 0) {
                // issue V(kb2=1) now: covered by softmax0 + PV0
                const uint16_t* vp = vbase + ((size_t)(2 * it + 1) * 4) * 512;
#pragma unroll
                for (int j = 0; j < 4; j++) vf1[j] = *(const bf16x8*)(vp + j * 512);
            }

            // softmax (static max): p = exp2(S + bias*log2e)
            float p[16];
            float lp = 0.f;
#pragma unroll
            for (int tt = 0; tt < 4; tt++) {
                uint2 uu = Bsh[(cur * 2 + kb2) * 512 + tt * 128 + qhalf * 64 + hi * 32 + c32];
                p[tt * 4 + 0] = exp2_fast(S[tt * 4 + 0] + u32lo_f(uu.x));
                p[tt * 4 + 1] = exp2_fast(S[tt * 4 + 1] + u32hi_f(uu.x));
                p[tt * 4 + 2] = exp2_fast(S[tt * 4 + 2] + u32lo_f(uu.y));
                p[tt * 4 + 3] = exp2_fast(S[tt * 4 + 3] + u32hi_f(uu.y));
                lp += (p[tt * 4 + 0] + p[tt * 4 + 1]) + (p[tt * 4 + 2] + p[tt * 4 + 3]);
            }
            lrun += lp;

            // m214 repack -> PV A-fragments (pa[0]: k 0..15, pa[1]: k 16..31 of sub-tile)
#pragma unroll
            for (int cp = 0; cp < 2; cp++) {
                uint32_t X0 = cvt_pk_bf16(p[8 * cp + 0], p[8 * cp + 1]);
                uint32_t X1 = cvt_pk_bf16(p[8 * cp + 2], p[8 * cp + 3]);
                uint32_t Y0 = cvt_pk_bf16(p[8 * cp + 4], p[8 * cp + 5]);
                uint32_t Y1 = cvt_pk_bf16(p[8 * cp + 6], p[8 * cp + 7]);
                p32swap(X0, Y0);
                p32swap(X1, Y1);
                union { uint32_t u[4]; bf16x8 v; } pu;
                pu.u[0] = X0; pu.u[1] = X1; pu.u[2] = Y0; pu.u[3] = Y1;
                pa[cp] = pu.v;
            }

            // O += P V for this sub-tile (V slot jj = db*2+c)
            __builtin_amdgcn_s_setprio(1);
#pragma unroll
            for (int c = 0; c < 2; c++)
#pragma unroll
                for (int db = 0; db < 2; db++) {
                    bf16x8 vv = kb2 ? vf1[db * 2 + c] : vf0[db * 2 + c];
                    accO[db] = __builtin_amdgcn_mfma_f32_32x32x16_bf16(pa[c], vv, accO[db], 0, 0, 0);
                }
            __builtin_amdgcn_s_setprio(0);
        }

        __syncthreads();   // one barrier per 64-k tile: stage/V/bias had compute in flight
    }

    // finalize: row-sum reduce + redistribute, O /= l, write bf16 [B, L, H*D]
    float s = lrun + __shfl_xor(lrun, 32, 64);
    float inv = 1.0f / s;                     // valid for q-row = c32 on all lanes
    float linv[16];
#pragma unroll
    for (int r = 0; r < 16; r++)
        linv[r] = __shfl(inv, (r & 3) + 8 * (r >> 2) + 4 * hi, 64);
#pragma unroll
    for (int r = 0; r < 16; r++) {
        int rowq = (r & 3) + 8 * (r >> 2) + 4 * hi;
        size_t rowbase = ((size_t)b * SEQ + q0w + rowq) * CMOD + h * DH;
        ob[rowbase + c32]      = f2bf(accO[0][r] * linv[r]);
        ob[rowbase + 32 + c32] = f2bf(accO[1][r] * linv[r]);
    }
}

// ---------------- launch ----------------
extern "C" void kernel_launch(void* const* d_in, const int* in_sizes, int n_in,
                              void* d_out, int out_size, void* d_ws, size_t ws_size,
                              hipStream_t stream) {
    const float* x             = (const float*)d_in[0];
    const float* attn_bias     = (const float*)d_in[1];
    const float* W_qkv         = (const float*)d_in[2];
    const float* q_bias        = (const float*)d_in[3];
    const float* v_bias        = (const float*)d_in[4];
    const float* scale_mul_log = (const float*)d_in[5];
    const float* W_proj        = (const float*)d_in[6];
    const float* b_proj        = (const float*)d_in[7];
    float* out = (float*)d_out;

    uint8_t* ws = (uint8_t*)d_ws;
    size_t off = 0;
    auto alloc = [&](size_t bytes) { uint8_t* p = ws + off; off += (bytes + 255) & ~(size_t)255; return p; };
    uint16_t* xb     = (uint16_t*)alloc((size_t)8192 * 1024 * 2);
    uint16_t* wqkvb  = (uint16_t*)alloc((size_t)3072 * 1024 * 2);
    uint16_t* wprojb = (uint16_t*)alloc((size_t)1024 * 1024 * 2);
    uint16_t* qb     = (uint16_t*)alloc((size_t)BATCH * NH * SEQ * DH * 2);
    uint16_t* kb     = (uint16_t*)alloc((size_t)BATCH * NH * SEQ * DH * 2);
    uint16_t* vtb    = (uint16_t*)alloc((size_t)BATCH * NH * SEQ * DH * 2);
    uint16_t* ob     = (uint16_t*)alloc((size_t)BATCH * SEQ * CMOD * 2);
    (void)ws_size;

    cvt_kernel<<<8192, 256, 0, stream>>>(x, xb, 8388608);
    cvt_kernel<<<3072, 256, 0, stream>>>(W_qkv, wqkvb, 3145728);
    cvt_kernel<<<1024, 256, 0, stream>>>(W_proj, wprojb, 1048576);

    dim3 g1(64, 24);
    gemm_bt_kernel<<<g1, 256, 0, stream>>>(xb, wqkvb, 8192, 3072, 1024, 0,
                                           qb, kb, vtb, q_bias, v_bias, scale_mul_log,
                                           nullptr, nullptr);

    attn_kernel<<<512, 512, 0, stream>>>(qb, kb, vtb, attn_bias, ob);

    dim3 g3(64, 8);
    gemm_bt_kernel<<<g3, 256, 0, stream>>>(ob, wprojb, 8192, 1024, 1024, 1,
                                           nullptr, nullptr, nullptr, nullptr, nullptr, nullptr,
                                           out, b_proj);
}

// Round 19
// 287.611 us; speedup vs baseline: 1.0983x; 1.0983x over previous
//
#include <hip/hip_runtime.h>
#include <cstdint>
#include <cstddef>

// Problem constants
#define BATCH 4
#define SEQ   2048
#define CMOD  1024
#define NH    16
#define DH    64
#define LOG100 4.6051701859880914f
#define LOG2E  1.4426950408889634f

typedef __attribute__((ext_vector_type(8))) short bf16x8;
typedef __attribute__((ext_vector_type(4))) float f32x4;
typedef __attribute__((ext_vector_type(16))) float f32x16;

__device__ __forceinline__ float u32lo_f(uint32_t u) {
    union { uint32_t i; float f; } x; x.i = u << 16; return x.f;
}
__device__ __forceinline__ float u32hi_f(uint32_t u) {
    union { uint32_t i; float f; } x; x.i = u & 0xFFFF0000u; return x.f;
}
__device__ __forceinline__ uint16_t f2bf(float f) {
    union { float f; uint32_t i; } x; x.f = f;
    uint32_t u = x.i;
    return (uint16_t)((u + 0x7FFFu + ((u >> 16) & 1u)) >> 16);  // RNE
}
__device__ __forceinline__ float exp2_fast(float x) {
    float r; asm("v_exp_f32 %0, %1" : "=v"(r) : "v"(x)); return r;
}
__device__ __forceinline__ uint32_t cvt_pk_bf16(float lo, float hi) {
    uint32_t r;
    asm("v_cvt_pk_bf16_f32 %0, %1, %2" : "=v"(r) : "v"(lo), "v"(hi));
    return r;
}
__device__ __forceinline__ void p32swap(uint32_t& x, uint32_t& y) {
#if __has_builtin(__builtin_amdgcn_permlane32_swap)
    auto r = __builtin_amdgcn_permlane32_swap(x, y, false, false);
    x = r[0]; y = r[1];
#else
    asm volatile("v_permlane32_swap_b32 %0, %1\n\ts_nop 1" : "+v"(x), "+v"(y));
#endif
}

__device__ __forceinline__ void gload_lds16(const void* g, void* l) {
    __builtin_amdgcn_global_load_lds(
        (const __attribute__((address_space(1))) uint32_t*)g,
        (__attribute__((address_space(3))) uint32_t*)l,
        16, 0, 0);
}

// ---------------- fp32 -> bf16 convert ----------------
__global__ __launch_bounds__(256) void cvt_kernel(const float* __restrict__ in,
                                                  uint16_t* __restrict__ out, int n) {
    int i = (blockIdx.x * 256 + threadIdx.x) * 4;
    if (i >= n) return;
    float4 f = *(const float4*)(in + i);
    ushort4 o;
    o.x = f2bf(f.x); o.y = f2bf(f.y); o.z = f2bf(f.z); o.w = f2bf(f.w);
    *(ushort4*)(out + i) = o;
}

// ---------------- bf16 GEMM, B-transposed input (m97 structure) ----------------
// mode 0: QKV epilogue. q/k normalized (q also * scale_h*log2e), then written in
// MFMA-FRAGMENT ORDER so attention can stage with lane-linear gload_lds:
//   q/k: addr = ((bh*64 + (l>>5))*4 + (d>>4))*512 + ((d>>3)&1)*256 + (l&31)*8 + (d&7)
//   v  : addr = ((bh*64 + (l>>5))*4 + (d>>5)*2 + ((l>>4)&1))*512
//               + (((l>>3)&1)*32 + (d&31))*8 + (l&7)
// mode 1: proj epilogue -> fp32 out + b_proj (unchanged).
__global__ __launch_bounds__(256) void gemm_bt_kernel(
    const uint16_t* __restrict__ A, const uint16_t* __restrict__ B,
    int M, int N, int K, int mode,
    uint16_t* __restrict__ qb, uint16_t* __restrict__ kb, uint16_t* __restrict__ vtb,
    const float* __restrict__ q_bias, const float* __restrict__ v_bias,
    const float* __restrict__ scale_mul_log,
    float* __restrict__ outp, const float* __restrict__ b_proj)
{
    __shared__ __align__(16) uint16_t As[128 * 32];
    __shared__ __align__(16) uint16_t Bs[128 * 32];
    const int t = threadIdx.x;
    const int wave = t >> 6, lane = t & 63;
    const int g = lane >> 4, c16 = lane & 15;
    const int m0 = blockIdx.x * 128, n0 = blockIdx.y * 128;
    const int wm = (wave >> 1) * 64, wn = (wave & 1) * 64;

    f32x4 acc[4][4];
#pragma unroll
    for (int mt = 0; mt < 4; mt++)
#pragma unroll
        for (int nt = 0; nt < 4; nt++) acc[mt][nt] = (f32x4){0.f, 0.f, 0.f, 0.f};

    for (int k0 = 0; k0 < K; k0 += 32) {
        __syncthreads();
#pragma unroll
        for (int i = 0; i < 2; i++) {
            int cc = i * 256 + t;           // 512 chunks of 8 elems
            int row = cc >> 2, col = (cc & 3) * 8;
            gload_lds16(A + (size_t)(m0 + row) * K + k0 + col, &As[cc * 8]);
            gload_lds16(B + (size_t)(n0 + row) * K + k0 + col, &Bs[cc * 8]);
        }
        __syncthreads();
        bf16x8 af[4], bfv[4];
#pragma unroll
        for (int mt = 0; mt < 4; mt++)
            af[mt] = *(const bf16x8*)&As[(wm + mt * 16 + c16) * 32 + g * 8];
#pragma unroll
        for (int nt = 0; nt < 4; nt++)
            bfv[nt] = *(const bf16x8*)&Bs[(wn + nt * 16 + c16) * 32 + g * 8];
#pragma unroll
        for (int mt = 0; mt < 4; mt++)
#pragma unroll
            for (int nt = 0; nt < 4; nt++)
                acc[mt][nt] = __builtin_amdgcn_mfma_f32_16x16x32_bf16(af[mt], bfv[nt], acc[mt][nt], 0, 0, 0);
    }

    if (mode == 0) {
        const int colbase = n0 + wn;          // multiple of 64 -> single (tt, head) per wave
        const int tt = colbase >> 10;
        const int cc0 = colbase & 1023;
        const int hh = cc0 >> 6;
        float qmul = 1.0f;
        if (tt == 0) qmul = __expf(fminf(scale_mul_log[hh], LOG100)) * LOG2E;
#pragma unroll
        for (int mt = 0; mt < 4; mt++) {
            float vals[4][4];
            float n2[4] = {0.f, 0.f, 0.f, 0.f};
#pragma unroll
            for (int nt = 0; nt < 4; nt++) {
                const int ci = cc0 + nt * 16 + c16;   // 0..1023 within qkv third
                float badd = 0.f;
                if (tt == 0) badd = q_bias[ci];
                else if (tt == 2) badd = v_bias[ci];
#pragma unroll
                for (int r = 0; r < 4; r++) {
                    float v = acc[mt][nt][r] + badd;
                    vals[nt][r] = v;
                    n2[r] += v * v;
                }
            }
            float rs[4];
            if (tt < 2) {   // L2-normalize q (with scale*log2e) and k over the 64-wide head dim
#pragma unroll
                for (int r = 0; r < 4; r++) {
                    float s = n2[r];
                    s += __shfl_xor(s, 1, 64);
                    s += __shfl_xor(s, 2, 64);
                    s += __shfl_xor(s, 4, 64);
                    s += __shfl_xor(s, 8, 64);
                    rs[r] = qmul / fmaxf(sqrtf(s), 1e-12f);
                }
            } else {
#pragma unroll
                for (int r = 0; r < 4; r++) rs[r] = 1.0f;
            }
#pragma unroll
            for (int nt = 0; nt < 4; nt++) {
                const int dd = (cc0 + nt * 16 + c16) & 63;
#pragma unroll
                for (int r = 0; r < 4; r++) {
                    const int row = m0 + wm + mt * 16 + g * 4 + r;   // b*2048 + l
                    const int bb = row >> 11, ll = row & 2047;
                    const size_t bhx = (size_t)bb * NH + hh;
                    const uint16_t val = f2bf(vals[nt][r] * rs[r]);
                    if (tt < 2) {
                        size_t addr = ((bhx * 64 + (ll >> 5)) * 4 + (dd >> 4)) * 512
                                      + ((dd >> 3) & 1) * 256 + (ll & 31) * 8 + (dd & 7);
                        if (tt == 0) qb[addr] = val; else kb[addr] = val;
                    } else {
                        size_t addr = ((bhx * 64 + (ll >> 5)) * 4 + (dd >> 5) * 2 + ((ll >> 4) & 1)) * 512
                                      + (((ll >> 3) & 1) * 32 + (dd & 31)) * 8 + (ll & 7);
                        vtb[addr] = val;
                    }
                }
            }
        }
    } else {
#pragma unroll
        for (int mt = 0; mt < 4; mt++)
#pragma unroll
            for (int nt = 0; nt < 4; nt++)
#pragma unroll
                for (int r = 0; r < 4; r++) {
                    int row = m0 + wm + mt * 16 + g * 4 + r;
                    int col = n0 + wn + nt * 16 + c16;
                    outp[(size_t)row * N + col] = acc[mt][nt][r] + b_proj[col];
                }
    }
}

// ---------------- fused cosine-sim flash attention (R16 + T5 setprio) ----------------
// R16 VERBATIM (best round, 280.2 us total) with ONE change: s_setprio(1/0) around the
// two MFMA clusters (T5, m191: attn +4-7% when waves are phase-diverse — our 8 waves
// drift between barriers via split staging roles). Single-variable A/B vs R16.
// Structure: grid 512, XCD-pinned heads (xcd=bid&7, h=xcd*2+(inner&1), qt=inner>>1);
// 8 waves: wave w8 -> batch b=w8&3, qhalf=w8>>2; KVBLK=32; K/V dbuf fragment-linear
// LDS (waves 0-3 stage K, 4-7 stage V); dbuf Bsh bias + regs(it+2) prefetch;
// swapped mfma(K,Q) 32x32x16, static-max softmax, cvt_pk+permlane32 repack.
__global__ __launch_bounds__(512, 4) void attn_kernel(
    const uint16_t* __restrict__ qfrag, const uint16_t* __restrict__ kfrag,
    const uint16_t* __restrict__ vfrag, const float* __restrict__ bias,
    uint16_t* __restrict__ ob)
{
    __shared__ __align__(16) uint16_t KsL[2 * 4 * 4 * 512];  // [buf][batch][slot][lane*8] 32 KB
    __shared__ __align__(16) uint16_t VsL[2 * 4 * 4 * 512];  // 32 KB
    __shared__ __align__(16) uint2    Bsh[2 * 512];          // [buf][unit] bf16x4, 8 KB

    const int t = threadIdx.x;
    const int w8 = t >> 6, lane = t & 63;
    const int b = w8 & 3, qhalf = w8 >> 2;     // batch, q-half of the 64-row tile
    const int c32 = lane & 31, hi = lane >> 5;

    // XCD-pinned (h, qt) decode
    const int bid = blockIdx.x;
    const int xcd = bid & 7;
    const int inner = bid >> 3;                // 0..63
    const int h = xcd * 2 + (inner & 1);       // 0..15
    const int qt = inner >> 1;                 // 0..31
    const int q0w = qt * 64 + qhalf * 32;      // this wave's 32 q-rows
    const size_t bh = (size_t)b * NH + h;

    // Q fragments: 4 d-slots for this wave's 32 rows (frag-ordered workspace)
    bf16x8 qf[4];
#pragma unroll
    for (int s = 0; s < 4; s++)
        qf[s] = *(const bf16x8*)(qfrag +
            ((bh * 64 + (size_t)(qt * 2 + qhalf)) * 4 + s) * 512 + hi * 256 + c32 * 8);

    // staging: waves 0-3 stage K(batch w8), waves 4-7 stage V(batch w8-4); 4 gloads each
    auto stage = [&](int tl, int buf) {
        if (w8 < 4) {
            const uint16_t* kp = kfrag + (((size_t)w8 * NH + h) * 64 + tl) * 4 * 512 + lane * 8;
#pragma unroll
            for (int s = 0; s < 4; s++)
                gload_lds16(kp + s * 512, &KsL[((buf * 4 + w8) * 4 + s) * 512 + lane * 8]);
        } else {
            const int bb = w8 - 4;
            const uint16_t* vp = vfrag + (((size_t)bb * NH + h) * 64 + tl) * 4 * 512 + lane * 8;
#pragma unroll
            for (int s = 0; s < 4; s++)
                gload_lds16(vp + s * 512, &VsL[((buf * 4 + bb) * 4 + s) * 512 + lane * 8]);
        }
    };

    // bias cooperative mapping: 512 threads x 1 float4 = the [64 q][32 k] tile.
    const int brow = t >> 3, kch = t & 7;
    const float* bgl = bias + ((size_t)h * SEQ + qt * 64 + brow) * SEQ + kch * 4;
    const int u0 = (kch >> 1) * 128 + (brow >> 5) * 64 + (kch & 1) * 32 + (brow & 31);

    auto writeBsh = [&](int buf, float4 a) {
        Bsh[buf * 512 + u0] =
            make_uint2(cvt_pk_bf16(a.x * LOG2E, a.y * LOG2E),
                       cvt_pk_bf16(a.z * LOG2E, a.w * LOG2E));
    };

    f32x16 accO[2];
#pragma unroll
    for (int db = 0; db < 2; db++)
#pragma unroll
        for (int i = 0; i < 16; i++) accO[db][i] = 0.f;
    float lrun = 0.f;

    // prologue: stage(0) + bias(0) -> LDS; bias(1) regs in flight
    float4 a0 = *(const float4*)(bgl);
    float4 br0 = *(const float4*)(bgl + 32);
    stage(0, 0);
    writeBsh(0, a0);
    __syncthreads();

    for (int it = 0; it < 64; ++it) {
        const int cur = it & 1;
        if (it < 63) {
            const int nb = cur ^ 1;
            writeBsh(nb, br0);                       // bias(it+1) -> Bsh[nb]
            int n2 = it + 2; if (n2 > 63) n2 = 63;
            br0 = *(const float4*)(bgl + n2 * 32);   // bias regs(it+2)
            stage(it + 1, nb);                       // K/V DMA flies through compute
        }

        // ---- compute tile it from buf[cur] ----
        bf16x8 kf[4];
#pragma unroll
        for (int s = 0; s < 4; s++)
            kf[s] = *(const bf16x8*)&KsL[((cur * 4 + b) * 4 + s) * 512 + lane * 8];

        // S^T = K Q^T : reg r -> k_local = (r&3)+8*(r>>2)+4*hi ; q-row = c32
        f32x16 S;
#pragma unroll
        for (int i = 0; i < 16; i++) S[i] = 0.f;
        __builtin_amdgcn_s_setprio(1);
#pragma unroll
        for (int s = 0; s < 4; s++)
            S = __builtin_amdgcn_mfma_f32_32x32x16_bf16(kf[s], qf[s], S, 0, 0, 0);
        __builtin_amdgcn_s_setprio(0);

        // softmax (static max): p = exp2(S + bias*log2e); Bsh read 512B/wave (2-way free)
        float p[16];
        float lp = 0.f;
#pragma unroll
        for (int tt = 0; tt < 4; tt++) {
            uint2 uu = Bsh[cur * 512 + tt * 128 + qhalf * 64 + hi * 32 + c32];
            p[tt * 4 + 0] = exp2_fast(S[tt * 4 + 0] + u32lo_f(uu.x));
            p[tt * 4 + 1] = exp2_fast(S[tt * 4 + 1] + u32hi_f(uu.x));
            p[tt * 4 + 2] = exp2_fast(S[tt * 4 + 2] + u32lo_f(uu.y));
            p[tt * 4 + 3] = exp2_fast(S[tt * 4 + 3] + u32hi_f(uu.y));
            lp += (p[tt * 4 + 0] + p[tt * 4 + 1]) + (p[tt * 4 + 2] + p[tt * 4 + 3]);
        }
        lrun += lp;

        // m214 repack -> PV A-fragments (pa[0]: k 0..15, pa[1]: k 16..31)
        bf16x8 pa[2];
#pragma unroll
        for (int cp = 0; cp < 2; cp++) {
            uint32_t X0 = cvt_pk_bf16(p[8 * cp + 0], p[8 * cp + 1]);
            uint32_t X1 = cvt_pk_bf16(p[8 * cp + 2], p[8 * cp + 3]);
            uint32_t Y0 = cvt_pk_bf16(p[8 * cp + 4], p[8 * cp + 5]);
            uint32_t Y1 = cvt_pk_bf16(p[8 * cp + 6], p[8 * cp + 7]);
            p32swap(X0, Y0);
            p32swap(X1, Y1);
            union { uint32_t u[4]; bf16x8 v; } pu;
            pu.u[0] = X0; pu.u[1] = X1; pu.u[2] = Y0; pu.u[3] = Y1;
            pa[cp] = pu.v;
        }

        // O += P V : V slot jj = db*2+c holds V^T[db*32+c32][(2c+hi)*8..]
        __builtin_amdgcn_s_setprio(1);
#pragma unroll
        for (int c = 0; c < 2; c++)
#pragma unroll
            for (int db = 0; db < 2; db++) {
                bf16x8 vf = *(const bf16x8*)&VsL[((cur * 4 + b) * 4 + db * 2 + c) * 512 + lane * 8];
                accO[db] = __builtin_amdgcn_mfma_f32_32x32x16_bf16(pa[c], vf, accO[db], 0, 0, 0);
            }
        __builtin_amdgcn_s_setprio(0);

        __syncthreads();   // drain lands here: stage(it+1) had the whole compute in flight
    }

    // finalize: row-sum reduce + redistribute, O /= l, write bf16 [B, L, H*D]
    float s = lrun + __shfl_xor(lrun, 32, 64);
    float inv = 1.0f / s;                     // valid for q-row = c32 on all lanes
    float linv[16];
#pragma unroll
    for (int r = 0; r < 16; r++)
        linv[r] = __shfl(inv, (r & 3) + 8 * (r >> 2) + 4 * hi, 64);
#pragma unroll
    for (int r = 0; r < 16; r++) {
        int rowq = (r & 3) + 8 * (r >> 2) + 4 * hi;
        size_t rowbase = ((size_t)b * SEQ + q0w + rowq) * CMOD + h * DH;
        ob[rowbase + c32]      = f2bf(accO[0][r] * linv[r]);
        ob[rowbase + 32 + c32] = f2bf(accO[1][r] * linv[r]);
    }
}

// ---------------- launch ----------------
extern "C" void kernel_launch(void* const* d_in, const int* in_sizes, int n_in,
                              void* d_out, int out_size, void* d_ws, size_t ws_size,
                              hipStream_t stream) {
    const float* x             = (const float*)d_in[0];
    const float* attn_bias     = (const float*)d_in[1];
    const float* W_qkv         = (const float*)d_in[2];
    const float* q_bias        = (const float*)d_in[3];
    const float* v_bias        = (const float*)d_in[4];
    const float* scale_mul_log = (const float*)d_in[5];
    const float* W_proj        = (const float*)d_in[6];
    const float* b_proj        = (const float*)d_in[7];
    float* out = (float*)d_out;

    uint8_t* ws = (uint8_t*)d_ws;
    size_t off = 0;
    auto alloc = [&](size_t bytes) { uint8_t* p = ws + off; off += (bytes + 255) & ~(size_t)255; return p; };
    uint16_t* xb     = (uint16_t*)alloc((size_t)8192 * 1024 * 2);
    uint16_t* wqkvb  = (uint16_t*)alloc((size_t)3072 * 1024 * 2);
    uint16_t* wprojb = (uint16_t*)alloc((size_t)1024 * 1024 * 2);
    uint16_t* qb     = (uint16_t*)alloc((size_t)BATCH * NH * SEQ * DH * 2);
    uint16_t* kb     = (uint16_t*)alloc((size_t)BATCH * NH * SEQ * DH * 2);
    uint16_t* vtb    = (uint16_t*)alloc((size_t)BATCH * NH * SEQ * DH * 2);
    uint16_t* ob     = (uint16_t*)alloc((size_t)BATCH * SEQ * CMOD * 2);
    (void)ws_size;

    cvt_kernel<<<8192, 256, 0, stream>>>(x, xb, 8388608);
    cvt_kernel<<<3072, 256, 0, stream>>>(W_qkv, wqkvb, 3145728);
    cvt_kernel<<<1024, 256, 0, stream>>>(W_proj, wprojb, 1048576);

    dim3 g1(64, 24);
    gemm_bt_kernel<<<g1, 256, 0, stream>>>(xb, wqkvb, 8192, 3072, 1024, 0,
                                           qb, kb, vtb, q_bias, v_bias, scale_mul_log,
                                           nullptr, nullptr);

    attn_kernel<<<512, 512, 0, stream>>>(qb, kb, vtb, attn_bias, ob);

    dim3 g3(64, 8);
    gemm_bt_kernel<<<g3, 256, 0, stream>>>(ob, wprojb, 8192, 1024, 1024, 1,
                                           nullptr, nullptr, nullptr, nullptr, nullptr, nullptr,
                                           out, b_proj);
}

// Round 20
// 278.882 us; speedup vs baseline: 1.1327x; 1.0313x over previous
//
#include <hip/hip_runtime.h>
#include <cstdint>
#include <cstddef>

// Problem constants
#define BATCH 4
#define SEQ   2048
#define CMOD  1024
#define NH    16
#define DH    64
#define LOG100 4.6051701859880914f
#define LOG2E  1.4426950408889634f

typedef __attribute__((ext_vector_type(8))) short bf16x8;
typedef __attribute__((ext_vector_type(4))) float f32x4;
typedef __attribute__((ext_vector_type(16))) float f32x16;

__device__ __forceinline__ float u32lo_f(uint32_t u) {
    union { uint32_t i; float f; } x; x.i = u << 16; return x.f;
}
__device__ __forceinline__ float u32hi_f(uint32_t u) {
    union { uint32_t i; float f; } x; x.i = u & 0xFFFF0000u; return x.f;
}
__device__ __forceinline__ uint16_t f2bf(float f) {
    union { float f; uint32_t i; } x; x.f = f;
    uint32_t u = x.i;
    return (uint16_t)((u + 0x7FFFu + ((u >> 16) & 1u)) >> 16);  // RNE
}
__device__ __forceinline__ float exp2_fast(float x) {
    float r; asm("v_exp_f32 %0, %1" : "=v"(r) : "v"(x)); return r;
}
__device__ __forceinline__ uint32_t cvt_pk_bf16(float lo, float hi) {
    uint32_t r;
    asm("v_cvt_pk_bf16_f32 %0, %1, %2" : "=v"(r) : "v"(lo), "v"(hi));
    return r;
}
__device__ __forceinline__ void p32swap(uint32_t& x, uint32_t& y) {
#if __has_builtin(__builtin_amdgcn_permlane32_swap)
    auto r = __builtin_amdgcn_permlane32_swap(x, y, false, false);
    x = r[0]; y = r[1];
#else
    asm volatile("v_permlane32_swap_b32 %0, %1\n\ts_nop 1" : "+v"(x), "+v"(y));
#endif
}

__device__ __forceinline__ void gload_lds16(const void* g, void* l) {
    __builtin_amdgcn_global_load_lds(
        (const __attribute__((address_space(1))) uint32_t*)g,
        (__attribute__((address_space(3))) uint32_t*)l,
        16, 0, 0);
}

// ---------------- fp32 -> bf16 convert ----------------
__global__ __launch_bounds__(256) void cvt_kernel(const float* __restrict__ in,
                                                  uint16_t* __restrict__ out, int n) {
    int i = (blockIdx.x * 256 + threadIdx.x) * 4;
    if (i >= n) return;
    float4 f = *(const float4*)(in + i);
    ushort4 o;
    o.x = f2bf(f.x); o.y = f2bf(f.y); o.z = f2bf(f.z); o.w = f2bf(f.w);
    *(ushort4*)(out + i) = o;
}

// ---------------- bf16 GEMM, B-transposed input (m97 structure) ----------------
// mode 0: QKV epilogue. q/k normalized (q also * scale_h*log2e), then written in
// MFMA-FRAGMENT ORDER so attention can stage with lane-linear gload_lds:
//   q/k: addr = ((bh*64 + (l>>5))*4 + (d>>4))*512 + ((d>>3)&1)*256 + (l&31)*8 + (d&7)
//   v  : addr = ((bh*64 + (l>>5))*4 + (d>>5)*2 + ((l>>4)&1))*512
//               + (((l>>3)&1)*32 + (d&31))*8 + (l&7)
// mode 1: proj epilogue -> fp32 out + b_proj (unchanged).
__global__ __launch_bounds__(256) void gemm_bt_kernel(
    const uint16_t* __restrict__ A, const uint16_t* __restrict__ B,
    int M, int N, int K, int mode,
    uint16_t* __restrict__ qb, uint16_t* __restrict__ kb, uint16_t* __restrict__ vtb,
    const float* __restrict__ q_bias, const float* __restrict__ v_bias,
    const float* __restrict__ scale_mul_log,
    float* __restrict__ outp, const float* __restrict__ b_proj)
{
    __shared__ __align__(16) uint16_t As[128 * 32];
    __shared__ __align__(16) uint16_t Bs[128 * 32];
    const int t = threadIdx.x;
    const int wave = t >> 6, lane = t & 63;
    const int g = lane >> 4, c16 = lane & 15;
    const int m0 = blockIdx.x * 128, n0 = blockIdx.y * 128;
    const int wm = (wave >> 1) * 64, wn = (wave & 1) * 64;

    f32x4 acc[4][4];
#pragma unroll
    for (int mt = 0; mt < 4; mt++)
#pragma unroll
        for (int nt = 0; nt < 4; nt++) acc[mt][nt] = (f32x4){0.f, 0.f, 0.f, 0.f};

    for (int k0 = 0; k0 < K; k0 += 32) {
        __syncthreads();
#pragma unroll
        for (int i = 0; i < 2; i++) {
            int cc = i * 256 + t;           // 512 chunks of 8 elems
            int row = cc >> 2, col = (cc & 3) * 8;
            gload_lds16(A + (size_t)(m0 + row) * K + k0 + col, &As[cc * 8]);
            gload_lds16(B + (size_t)(n0 + row) * K + k0 + col, &Bs[cc * 8]);
        }
        __syncthreads();
        bf16x8 af[4], bfv[4];
#pragma unroll
        for (int mt = 0; mt < 4; mt++)
            af[mt] = *(const bf16x8*)&As[(wm + mt * 16 + c16) * 32 + g * 8];
#pragma unroll
        for (int nt = 0; nt < 4; nt++)
            bfv[nt] = *(const bf16x8*)&Bs[(wn + nt * 16 + c16) * 32 + g * 8];
#pragma unroll
        for (int mt = 0; mt < 4; mt++)
#pragma unroll
            for (int nt = 0; nt < 4; nt++)
                acc[mt][nt] = __builtin_amdgcn_mfma_f32_16x16x32_bf16(af[mt], bfv[nt], acc[mt][nt], 0, 0, 0);
    }

    if (mode == 0) {
        const int colbase = n0 + wn;          // multiple of 64 -> single (tt, head) per wave
        const int tt = colbase >> 10;
        const int cc0 = colbase & 1023;
        const int hh = cc0 >> 6;
        float qmul = 1.0f;
        if (tt == 0) qmul = __expf(fminf(scale_mul_log[hh], LOG100)) * LOG2E;
#pragma unroll
        for (int mt = 0; mt < 4; mt++) {
            float vals[4][4];
            float n2[4] = {0.f, 0.f, 0.f, 0.f};
#pragma unroll
            for (int nt = 0; nt < 4; nt++) {
                const int ci = cc0 + nt * 16 + c16;   // 0..1023 within qkv third
                float badd = 0.f;
                if (tt == 0) badd = q_bias[ci];
                else if (tt == 2) badd = v_bias[ci];
#pragma unroll
                for (int r = 0; r < 4; r++) {
                    float v = acc[mt][nt][r] + badd;
                    vals[nt][r] = v;
                    n2[r] += v * v;
                }
            }
            float rs[4];
            if (tt < 2) {   // L2-normalize q (with scale*log2e) and k over the 64-wide head dim
#pragma unroll
                for (int r = 0; r < 4; r++) {
                    float s = n2[r];
                    s += __shfl_xor(s, 1, 64);
                    s += __shfl_xor(s, 2, 64);
                    s += __shfl_xor(s, 4, 64);
                    s += __shfl_xor(s, 8, 64);
                    rs[r] = qmul / fmaxf(sqrtf(s), 1e-12f);
                }
            } else {
#pragma unroll
                for (int r = 0; r < 4; r++) rs[r] = 1.0f;
            }
#pragma unroll
            for (int nt = 0; nt < 4; nt++) {
                const int dd = (cc0 + nt * 16 + c16) & 63;
#pragma unroll
                for (int r = 0; r < 4; r++) {
                    const int row = m0 + wm + mt * 16 + g * 4 + r;   // b*2048 + l
                    const int bb = row >> 11, ll = row & 2047;
                    const size_t bhx = (size_t)bb * NH + hh;
                    const uint16_t val = f2bf(vals[nt][r] * rs[r]);
                    if (tt < 2) {
                        size_t addr = ((bhx * 64 + (ll >> 5)) * 4 + (dd >> 4)) * 512
                                      + ((dd >> 3) & 1) * 256 + (ll & 31) * 8 + (dd & 7);
                        if (tt == 0) qb[addr] = val; else kb[addr] = val;
                    } else {
                        size_t addr = ((bhx * 64 + (ll >> 5)) * 4 + (dd >> 5) * 2 + ((ll >> 4) & 1)) * 512
                                      + (((ll >> 3) & 1) * 32 + (dd & 31)) * 8 + (ll & 7);
                        vtb[addr] = val;
                    }
                }
            }
        }
    } else {
#pragma unroll
        for (int mt = 0; mt < 4; mt++)
#pragma unroll
            for (int nt = 0; nt < 4; nt++)
#pragma unroll
                for (int r = 0; r < 4; r++) {
                    int row = m0 + wm + mt * 16 + g * 4 + r;
                    int col = n0 + wn + nt * 16 + c16;
                    outp[(size_t)row * N + col] = acc[mt][nt][r] + b_proj[col];
                }
    }
}

// ---------------- fused cosine-sim flash attention (R16 consolidation) ----------------
// This is R16 byte-exact — the verified best configuration (280.2 us total):
// grid 512, XCD-pinned heads (xcd=bid&7, h=xcd*2+(inner&1), qt=inner>>1 -> each XCD's
// K/V working set = 4 MB = its L2); 8 waves (512 thr): wave w8 -> batch b=w8&3,
// qhalf=w8>>2 (32 q-rows each); KVBLK=32; double-buffered fragment-linear K/V LDS
// (waves 0-3 stage K, 4-7 stage V via gload_lds, lane-linear -> conflict-free);
// dbuf Bsh bias (coalesced row-linear loads, x LOG2E, bf16) + regs(it+2) prefetch;
// swapped mfma(K,Q) 32x32x16 (m74/m101 layout), static-max softmax (bounded logits),
// cvt_pk+permlane32 repack (m214-v22). Probes falsified: V-direct (R17 +8us),
// KVBLK=64 (R18 +35us), setprio (R19 ~0), counted-vmcnt (R12/13), sched_barrier (R12).
__global__ __launch_bounds__(512, 4) void attn_kernel(
    const uint16_t* __restrict__ qfrag, const uint16_t* __restrict__ kfrag,
    const uint16_t* __restrict__ vfrag, const float* __restrict__ bias,
    uint16_t* __restrict__ ob)
{
    __shared__ __align__(16) uint16_t KsL[2 * 4 * 4 * 512];  // [buf][batch][slot][lane*8] 32 KB
    __shared__ __align__(16) uint16_t VsL[2 * 4 * 4 * 512];  // 32 KB
    __shared__ __align__(16) uint2    Bsh[2 * 512];          // [buf][unit] bf16x4, 8 KB

    const int t = threadIdx.x;
    const int w8 = t >> 6, lane = t & 63;
    const int b = w8 & 3, qhalf = w8 >> 2;     // batch, q-half of the 64-row tile
    const int c32 = lane & 31, hi = lane >> 5;

    // XCD-pinned (h, qt) decode
    const int bid = blockIdx.x;
    const int xcd = bid & 7;
    const int inner = bid >> 3;                // 0..63
    const int h = xcd * 2 + (inner & 1);       // 0..15
    const int qt = inner >> 1;                 // 0..31
    const int q0w = qt * 64 + qhalf * 32;      // this wave's 32 q-rows
    const size_t bh = (size_t)b * NH + h;

    // Q fragments: 4 d-slots for this wave's 32 rows (frag-ordered workspace)
    bf16x8 qf[4];
#pragma unroll
    for (int s = 0; s < 4; s++)
        qf[s] = *(const bf16x8*)(qfrag +
            ((bh * 64 + (size_t)(qt * 2 + qhalf)) * 4 + s) * 512 + hi * 256 + c32 * 8);

    // staging: waves 0-3 stage K(batch w8), waves 4-7 stage V(batch w8-4); 4 gloads each
    auto stage = [&](int tl, int buf) {
        if (w8 < 4) {
            const uint16_t* kp = kfrag + (((size_t)w8 * NH + h) * 64 + tl) * 4 * 512 + lane * 8;
#pragma unroll
            for (int s = 0; s < 4; s++)
                gload_lds16(kp + s * 512, &KsL[((buf * 4 + w8) * 4 + s) * 512 + lane * 8]);
        } else {
            const int bb = w8 - 4;
            const uint16_t* vp = vfrag + (((size_t)bb * NH + h) * 64 + tl) * 4 * 512 + lane * 8;
#pragma unroll
            for (int s = 0; s < 4; s++)
                gload_lds16(vp + s * 512, &VsL[((buf * 4 + bb) * 4 + s) * 512 + lane * 8]);
        }
    };

    // bias cooperative mapping: 512 threads x 1 float4 = the [64 q][32 k] tile.
    // thread t -> row = t>>3 (0..63), granule kch = t&7 (k = kch*4..+4)
    // unit(g, qrow) = (g>>1)*128 + (qrow>>5)*64 + (g&1)*32 + (qrow&31)
    const int brow = t >> 3, kch = t & 7;
    const float* bgl = bias + ((size_t)h * SEQ + qt * 64 + brow) * SEQ + kch * 4;
    const int u0 = (kch >> 1) * 128 + (brow >> 5) * 64 + (kch & 1) * 32 + (brow & 31);

    auto writeBsh = [&](int buf, float4 a) {
        Bsh[buf * 512 + u0] =
            make_uint2(cvt_pk_bf16(a.x * LOG2E, a.y * LOG2E),
                       cvt_pk_bf16(a.z * LOG2E, a.w * LOG2E));
    };

    f32x16 accO[2];
#pragma unroll
    for (int db = 0; db < 2; db++)
#pragma unroll
        for (int i = 0; i < 16; i++) accO[db][i] = 0.f;
    float lrun = 0.f;

    // prologue: stage(0) + bias(0) -> LDS; bias(1) regs in flight
    float4 a0 = *(const float4*)(bgl);
    float4 br0 = *(const float4*)(bgl + 32);
    stage(0, 0);
    writeBsh(0, a0);
    __syncthreads();

    for (int it = 0; it < 64; ++it) {
        const int cur = it & 1;
        if (it < 63) {
            const int nb = cur ^ 1;
            writeBsh(nb, br0);                       // bias(it+1) -> Bsh[nb]
            int n2 = it + 2; if (n2 > 63) n2 = 63;
            br0 = *(const float4*)(bgl + n2 * 32);   // bias regs(it+2)
            stage(it + 1, nb);                       // K/V DMA flies through compute
        }

        // ---- compute tile it from buf[cur] ----
        bf16x8 kf[4];
#pragma unroll
        for (int s = 0; s < 4; s++)
            kf[s] = *(const bf16x8*)&KsL[((cur * 4 + b) * 4 + s) * 512 + lane * 8];

        // S^T = K Q^T : reg r -> k_local = (r&3)+8*(r>>2)+4*hi ; q-row = c32
        f32x16 S;
#pragma unroll
        for (int i = 0; i < 16; i++) S[i] = 0.f;
#pragma unroll
        for (int s = 0; s < 4; s++)
            S = __builtin_amdgcn_mfma_f32_32x32x16_bf16(kf[s], qf[s], S, 0, 0, 0);

        // softmax (static max): p = exp2(S + bias*log2e); Bsh read 512B/wave (2-way free)
        float p[16];
        float lp = 0.f;
#pragma unroll
        for (int tt = 0; tt < 4; tt++) {
            uint2 uu = Bsh[cur * 512 + tt * 128 + qhalf * 64 + hi * 32 + c32];
            p[tt * 4 + 0] = exp2_fast(S[tt * 4 + 0] + u32lo_f(uu.x));
            p[tt * 4 + 1] = exp2_fast(S[tt * 4 + 1] + u32hi_f(uu.x));
            p[tt * 4 + 2] = exp2_fast(S[tt * 4 + 2] + u32lo_f(uu.y));
            p[tt * 4 + 3] = exp2_fast(S[tt * 4 + 3] + u32hi_f(uu.y));
            lp += (p[tt * 4 + 0] + p[tt * 4 + 1]) + (p[tt * 4 + 2] + p[tt * 4 + 3]);
        }
        lrun += lp;

        // m214 repack -> PV A-fragments (pa[0]: k 0..15, pa[1]: k 16..31)
        bf16x8 pa[2];
#pragma unroll
        for (int cp = 0; cp < 2; cp++) {
            uint32_t X0 = cvt_pk_bf16(p[8 * cp + 0], p[8 * cp + 1]);
            uint32_t X1 = cvt_pk_bf16(p[8 * cp + 2], p[8 * cp + 3]);
            uint32_t Y0 = cvt_pk_bf16(p[8 * cp + 4], p[8 * cp + 5]);
            uint32_t Y1 = cvt_pk_bf16(p[8 * cp + 6], p[8 * cp + 7]);
            p32swap(X0, Y0);
            p32swap(X1, Y1);
            union { uint32_t u[4]; bf16x8 v; } pu;
            pu.u[0] = X0; pu.u[1] = X1; pu.u[2] = Y0; pu.u[3] = Y1;
            pa[cp] = pu.v;
        }

        // O += P V : V slot jj = db*2+c holds V^T[db*32+c32][(2c+hi)*8..]
#pragma unroll
        for (int c = 0; c < 2; c++)
#pragma unroll
            for (int db = 0; db < 2; db++) {
                bf16x8 vf = *(const bf16x8*)&VsL[((cur * 4 + b) * 4 + db * 2 + c) * 512 + lane * 8];
                accO[db] = __builtin_amdgcn_mfma_f32_32x32x16_bf16(pa[c], vf, accO[db], 0, 0, 0);
            }

        __syncthreads();   // drain lands here: stage(it+1) had the whole compute in flight
    }

    // finalize: row-sum reduce + redistribute, O /= l, write bf16 [B, L, H*D]
    float s = lrun + __shfl_xor(lrun, 32, 64);
    float inv = 1.0f / s;                     // valid for q-row = c32 on all lanes
    float linv[16];
#pragma unroll
    for (int r = 0; r < 16; r++)
        linv[r] = __shfl(inv, (r & 3) + 8 * (r >> 2) + 4 * hi, 64);
#pragma unroll
    for (int r = 0; r < 16; r++) {
        int rowq = (r & 3) + 8 * (r >> 2) + 4 * hi;
        size_t rowbase = ((size_t)b * SEQ + q0w + rowq) * CMOD + h * DH;
        ob[rowbase + c32]      = f2bf(accO[0][r] * linv[r]);
        ob[rowbase + 32 + c32] = f2bf(accO[1][r] * linv[r]);
    }
}

// ---------------- launch ----------------
extern "C" void kernel_launch(void* const* d_in, const int* in_sizes, int n_in,
                              void* d_out, int out_size, void* d_ws, size_t ws_size,
                              hipStream_t stream) {
    const float* x             = (const float*)d_in[0];
    const float* attn_bias     = (const float*)d_in[1];
    const float* W_qkv         = (const float*)d_in[2];
    const float* q_bias        = (const float*)d_in[3];
    const float* v_bias        = (const float*)d_in[4];
    const float* scale_mul_log = (const float*)d_in[5];
    const float* W_proj        = (const float*)d_in[6];
    const float* b_proj        = (const float*)d_in[7];
    float* out = (float*)d_out;

    uint8_t* ws = (uint8_t*)d_ws;
    size_t off = 0;
    auto alloc = [&](size_t bytes) { uint8_t* p = ws + off; off += (bytes + 255) & ~(size_t)255; return p; };
    uint16_t* xb     = (uint16_t*)alloc((size_t)8192 * 1024 * 2);
    uint16_t* wqkvb  = (uint16_t*)alloc((size_t)3072 * 1024 * 2);
    uint16_t* wprojb = (uint16_t*)alloc((size_t)1024 * 1024 * 2);
    uint16_t* qb     = (uint16_t*)alloc((size_t)BATCH * NH * SEQ * DH * 2);
    uint16_t* kb     = (uint16_t*)alloc((size_t)BATCH * NH * SEQ * DH * 2);
    uint16_t* vtb    = (uint16_t*)alloc((size_t)BATCH * NH * SEQ * DH * 2);
    uint16_t* ob     = (uint16_t*)alloc((size_t)BATCH * SEQ * CMOD * 2);
    (void)ws_size;

    cvt_kernel<<<8192, 256, 0, stream>>>(x, xb, 8388608);
    cvt_kernel<<<3072, 256, 0, stream>>>(W_qkv, wqkvb, 3145728);
    cvt_kernel<<<1024, 256, 0, stream>>>(W_proj, wprojb, 1048576);

    dim3 g1(64, 24);
    gemm_bt_kernel<<<g1, 256, 0, stream>>>(xb, wqkvb, 8192, 3072, 1024, 0,
                                           qb, kb, vtb, q_bias, v_bias, scale_mul_log,
                                           nullptr, nullptr);

    attn_kernel<<<512, 512, 0, stream>>>(qb, kb, vtb, attn_bias, ob);

    dim3 g3(64, 8);
    gemm_bt_kernel<<<g3, 256, 0, stream>>>(ob, wprojb, 8192, 1024, 1024, 1,
                                           nullptr, nullptr, nullptr, nullptr, nullptr, nullptr,
                                           out, b_proj);
}